// Round 1
// baseline (345.754 us; speedup 1.0000x reference)
//
#include <hip/hip_runtime.h>

// HashRouter: h = x @ W^T + b (T x 64), cand = popcount of sign bits per
// 32-output group; i0 = c0, i1 = c1 + (c1==c0).
// Outputs (float32, concat): weights[T][2]=0.5, indices[T][2], logits[T][64]=0.
//
// R4: occupancy fix. rocprof showed OccupancyPercent=11.5, VALUBusy=24.6,
// HBM=5.8% -> latency-bound at 2 waves/SIMD (grid 512 x 256thr = 2 blocks/CU
// was the cap). Same algorithm/LDS/DMA machinery, but 512-thread blocks with
// 16-way K-split: grid stays 512 -> 2 blocks/CU -> 16 waves/CU = 4 waves/SIMD
// (max at <=128 VGPR, forced by launch_bounds). The extra 16->8 reduce level
// is a free in-wave __shfl_xor(.,32) fold (kg pairs are the two 32-lane
// halves of a wave), so LDS stays 48 KB and the proven 8->4->2->1 LDS tree
// is reused unchanged with v = tid>>6.

constexpr int H_DIM  = 2048;
constexpr int NJ     = 64;             // hash outputs
constexpr int TOK    = 32;             // tokens per block
constexpr int KC     = 64;             // k-chunk (floats) staged per row
constexpr int NCHUNK = H_DIM / KC;     // 32
constexpr int XF     = TOK * KC;       // 2048 floats per x buffer
constexpr int WF     = NJ * KC;        // 4096 floats per w buffer
constexpr int BUF    = XF + WF;        // 6144 floats (24 KB) per buffer
constexpr int XSLOTS = XF / 4;         // 512 float4 slots (x region)
constexpr int NTHR   = 512;            // threads per block (8 waves)
constexpr int SLOTS  = BUF / 4;        // 1536 float4 slots per buffer

// Row swizzle for k4-column permutation. Inner-loop reads land <=2 addresses
// per bank-quad (2-way is free per m136).
__device__ __forceinline__ int sw_of(int row) {
    return (3 * (row >> 3) + ((row >> 2) & 1)) & 7;
}

// Async 16B global->LDS DMA. LDS dest is wave-uniform base + lane*16 (m104),
// so LDS layout is lane-linear and the swizzle is applied to the GLOBAL column
// instead: LDS[row][c4p] holds global column (c4p ^ sw_of(row)).
__device__ __forceinline__ void stage_chunk(const float* __restrict__ x,
                                            const float* __restrict__ w,
                                            float* smem, int fb,
                                            int tok0, int k0, int tid) {
#pragma unroll
    for (int it = 0; it < SLOTS / NTHR; ++it) {        // 3 iters
        const int slot = it * NTHR + tid;              // 1536 slots: 512 x, 1024 w
        const float* g;
        if (slot < XSLOTS) {
            const int row = slot >> 4, c4p = slot & 15;
            g = x + (size_t)(tok0 + row) * H_DIM + k0 + ((c4p ^ sw_of(row)) << 2);
        } else {
            const int s2 = slot - XSLOTS;
            const int row = s2 >> 4, c4p = s2 & 15;
            g = w + (size_t)row * H_DIM + k0 + ((c4p ^ sw_of(row)) << 2);
        }
        __builtin_amdgcn_global_load_lds(
            (const __attribute__((address_space(1))) void*)g,
            (__attribute__((address_space(3))) void*)(smem + fb + slot * 4),
            16, 0, 0);
    }
}

__global__ __launch_bounds__(NTHR, 4) void hash_router_kernel(
    const float* __restrict__ x,   // [T, H]
    const float* __restrict__ w,   // [64, H]
    const float* __restrict__ b,   // [64]
    float* __restrict__ out,       // [2T | 2T | 64T]
    int T)
{
    __shared__ float smem[2 * BUF];                 // 48 KB (also reduce area)
    __shared__ unsigned int bitw[TOK][2];

    const int tid = threadIdx.x;
    const int og  = tid & 7;          // outputs og*8 .. og*8+7
    const int tg  = (tid >> 3) & 3;   // tokens  tg*8 .. tg*8+7
    const int kg  = tid >> 5;         // K-sixteenth: k4 = kg per chunk (0..15)
    const int tok0 = blockIdx.x * TOK;

    if (tid < TOK * 2) ((unsigned int*)bitw)[tid] = 0u;

    float acc[8][8];
#pragma unroll
    for (int i = 0; i < 8; ++i)
#pragma unroll
        for (int j = 0; j < 8; ++j) acc[i][j] = 0.f;

    stage_chunk(x, w, smem, 0, tok0, 0, tid);

    for (int ch = 0; ch < NCHUNK; ++ch) {
        __builtin_amdgcn_s_waitcnt(0x0f70);   // vmcnt(0): chunk ch landed
        __syncthreads();
        if (ch + 1 < NCHUNK)                  // prefetch flies during compute
            stage_chunk(x, w, smem, ((ch + 1) & 1) * BUF, tok0, (ch + 1) * KC, tid);

        const int fb = (ch & 1) * BUF;
        const int k4 = kg;                    // one k4 per thread per chunk
        float4 xv[8];
#pragma unroll
        for (int i = 0; i < 8; ++i) {
            const int row = tg * 8 + i;
            xv[i] = *(const float4*)(smem + fb + row * KC + ((k4 ^ sw_of(row)) << 2));
        }
#pragma unroll
        for (int j = 0; j < 8; ++j) {
            const int row = og * 8 + j;
            const float4 wv = *(const float4*)(smem + fb + XF + row * KC + ((k4 ^ sw_of(row)) << 2));
#pragma unroll
            for (int i = 0; i < 8; ++i) {
                acc[i][j] += xv[i].x * wv.x;
                acc[i][j] += xv[i].y * wv.y;
                acc[i][j] += xv[i].z * wv.z;
                acc[i][j] += xv[i].w * wv.w;
            }
        }
    }

    // ---- K-split reduce: 16 -> 8 in-register (kg pairs are the two 32-lane
    // halves of each wave), then the 8 -> 4 -> 2 -> 1 LDS tree with v=tid>>6.
    __syncthreads();                      // buf readers done; smem reusable
#pragma unroll
    for (int i = 0; i < 8; ++i)
#pragma unroll
        for (int j = 0; j < 8; ++j)
            acc[i][j] += __shfl_xor(acc[i][j], 32, 64);

    const int v  = tid >> 6;              // wave index = folded K-eighth (0..7)
    const bool lo = (tid & 32) == 0;      // lower half-wave owns the pair-sum
    const int s  = tid & 31;              // (tg,og) slot id
    const int sw = s & 7;
#define ACC_PACK(f4) make_float4(acc[(f4) >> 1][((f4) & 1) * 4],     \
                                 acc[(f4) >> 1][((f4) & 1) * 4 + 1], \
                                 acc[(f4) >> 1][((f4) & 1) * 4 + 2], \
                                 acc[(f4) >> 1][((f4) & 1) * 4 + 3])
#define ACC_ADD(f4, val) { acc[(f4) >> 1][((f4) & 1) * 4]     += (val).x; \
                           acc[(f4) >> 1][((f4) & 1) * 4 + 1] += (val).y; \
                           acc[(f4) >> 1][((f4) & 1) * 4 + 2] += (val).z; \
                           acc[(f4) >> 1][((f4) & 1) * 4 + 3] += (val).w; }
    if (v >= 4 && lo) {
        float* base = smem + ((v - 4) * 32 + s) * 64;
#pragma unroll
        for (int f4 = 0; f4 < 16; ++f4) *(float4*)(base + ((f4 ^ sw) << 2)) = ACC_PACK(f4);
    }
    __syncthreads();
    if (v < 4 && lo) {
        const float* base = smem + (v * 32 + s) * 64;
#pragma unroll
        for (int f4 = 0; f4 < 16; ++f4) { float4 t = *(const float4*)(base + ((f4 ^ sw) << 2)); ACC_ADD(f4, t); }
    }
    __syncthreads();
    if ((v == 2 || v == 3) && lo) {
        float* base = smem + ((v - 2) * 32 + s) * 64;
#pragma unroll
        for (int f4 = 0; f4 < 16; ++f4) *(float4*)(base + ((f4 ^ sw) << 2)) = ACC_PACK(f4);
    }
    __syncthreads();
    if (v < 2 && lo) {
        const float* base = smem + (v * 32 + s) * 64;
#pragma unroll
        for (int f4 = 0; f4 < 16; ++f4) { float4 t = *(const float4*)(base + ((f4 ^ sw) << 2)); ACC_ADD(f4, t); }
    }
    __syncthreads();
    if (v == 1 && lo) {
        float* base = smem + s * 64;
#pragma unroll
        for (int f4 = 0; f4 < 16; ++f4) *(float4*)(base + ((f4 ^ sw) << 2)) = ACC_PACK(f4);
    }
    __syncthreads();

    if (v == 0 && lo) {                   // tids 0..31, one per (tg,og) tile
        const float* base = smem + s * 64;
#pragma unroll
        for (int f4 = 0; f4 < 16; ++f4) { float4 t = *(const float4*)(base + ((f4 ^ sw) << 2)); ACC_ADD(f4, t); }

        float bias[8];
#pragma unroll
        for (int j = 0; j < 8; ++j) bias[j] = b[og * 8 + j];

        // Sign extraction; |h| within fp32-noise of 0 -> exact fp64 recheck
        // (~100 dots GPU-wide, negligible).
        const float TH = 5e-5f;
#pragma unroll
        for (int i = 0; i < 8; ++i) {
            unsigned int byte = 0u;
#pragma unroll
            for (int j = 0; j < 8; ++j) {
                const float hv = acc[i][j] + bias[j];
                bool pos;
                if (__builtin_expect(fabsf(hv) < TH, 0)) {
                    const float* xr = x + (size_t)(tok0 + tg * 8 + i) * H_DIM;
                    const float* wr = w + (size_t)(og * 8 + j) * H_DIM;
                    double sd = (double)bias[j];
                    for (int k = 0; k < H_DIM; ++k)
                        sd += (double)xr[k] * (double)wr[k];
                    pos = (sd > 0.0);
                } else {
                    pos = (hv > 0.0f);
                }
                byte |= (pos ? 1u : 0u) << j;
            }
            // outs og*8.. all in 32-bit group og>>2; position within group
            // is irrelevant (only popcount matters)
            if (byte) atomicOr(&bitw[tg * 8 + i][og >> 2], byte << ((og & 3) * 8));
        }
    }
    __syncthreads();

    if (tid < TOK) {
        const int t  = tok0 + tid;
        const int c0 = __popc(bitw[tid][0]);
        const int c1 = __popc(bitw[tid][1]);
        const int i1 = c1 + ((c1 == c0) ? 1 : 0);
        float2 wq; wq.x = 0.5f; wq.y = 0.5f;
        *(float2*)(out + 2 * (size_t)t) = wq;
        float2 iq; iq.x = (float)c0; iq.y = (float)i1;
        *(float2*)(out + 2 * (size_t)T + 2 * (size_t)t) = iq;
    }

    // router_logits = 0 (d_out re-poisoned 0xAA before every timed launch)
    float4 z; z.x = 0.f; z.y = 0.f; z.z = 0.f; z.w = 0.f;
    float* lbase = out + 4 * (size_t)T + (size_t)tok0 * NJ;
#pragma unroll
    for (int i = tid; i < TOK * NJ / 4; i += NTHR)
        *(float4*)(lbase + i * 4) = z;
}

extern "C" void kernel_launch(void* const* d_in, const int* in_sizes, int n_in,
                              void* d_out, int out_size, void* d_ws, size_t ws_size,
                              hipStream_t stream) {
    const float* x = (const float*)d_in[0];
    const float* w = (const float*)d_in[1];
    const float* b = (const float*)d_in[2];
    float* out = (float*)d_out;
    const int T = in_sizes[0] / H_DIM;      // 16384
    const int grid = T / TOK;               // 512
    hash_router_kernel<<<dim3(grid), dim3(NTHR), 0, stream>>>(x, w, b, out, T);
}

// Round 2
// 344.084 us; speedup vs baseline: 1.0049x; 1.0049x over previous
//
#include <hip/hip_runtime.h>

// HashRouter: h = x @ W^T + b (T x 64), cand = popcount of sign bits per
// 32-output group; i0 = c0, i1 = c1 + (c1==c0).
// Outputs (float32, concat): weights[T][2]=0.5, indices[T][2], logits[T][64]=0.
//
// R5: occupancy via MORE BLOCKS, not bigger blocks. R4 (512thr, lb(512,4))
// spilled: VGPR capped at 64, WRITE_SIZE 4.3->29 MB of scratch -> regression.
// R5 keeps the proven 256-thread shape (124 VGPR, no spill) and halves the
// tile: TOK=16 -> grid=1024 -> 4 blocks/CU; LDS shrunk to exactly 40960 B
// (2 x (16+64)*64 floats, bitw overlaid post-loop) so 4 blocks fit the
// 160 KiB CU budget. 16 waves/CU = 4 waves/SIMD, 2x R3. K-split is 16-way
// (one k4/thread/chunk); the extra 16->4 fold is two free in-wave
// __shfl_xor butterflies (tid bits 4,5 == kg bits 0,1), then the verified
// swizzled LDS tree does 4->2->1 in 8 KB of the dead staging buffer.

constexpr int H_DIM  = 2048;
constexpr int NJ     = 64;             // hash outputs
constexpr int TOK    = 16;             // tokens per block
constexpr int KC     = 64;             // k-chunk (floats) staged per row
constexpr int NCHUNK = H_DIM / KC;     // 32
constexpr int XF     = TOK * KC;       // 1024 floats per x buffer
constexpr int WF     = NJ * KC;        // 4096 floats per w buffer
constexpr int BUF    = XF + WF;        // 5120 floats (20 KB) per buffer
constexpr int XSLOTS = XF / 4;         // 256 float4 slots (x region)
constexpr int NTHR   = 256;            // threads per block (4 waves)
constexpr int SLOTS  = BUF / 4;        // 1280 float4 slots per buffer

// Row swizzle for k4-column permutation. Inner-loop reads land evenly across
// bank-quads (wv: 32 distinct f4s, 4/quad even; xv: 8 distinct, 8-way bcast).
__device__ __forceinline__ int sw_of(int row) {
    return (3 * (row >> 3) + ((row >> 2) & 1)) & 7;
}

// Async 16B global->LDS DMA. LDS dest is wave-uniform base + lane*16 (m104),
// so LDS layout is lane-linear and the swizzle is applied to the GLOBAL column
// instead: LDS[row][c4p] holds global column (c4p ^ sw_of(row)).
__device__ __forceinline__ void stage_chunk(const float* __restrict__ x,
                                            const float* __restrict__ w,
                                            float* smem, int fb,
                                            int tok0, int k0, int tid) {
#pragma unroll
    for (int it = 0; it < SLOTS / NTHR; ++it) {        // 5 iters
        const int slot = it * NTHR + tid;              // 1280 slots: 256 x, 1024 w
        const float* g;
        if (slot < XSLOTS) {
            const int row = slot >> 4, c4p = slot & 15;
            g = x + (size_t)(tok0 + row) * H_DIM + k0 + ((c4p ^ sw_of(row)) << 2);
        } else {
            const int s2 = slot - XSLOTS;
            const int row = s2 >> 4, c4p = s2 & 15;
            g = w + (size_t)row * H_DIM + k0 + ((c4p ^ sw_of(row)) << 2);
        }
        __builtin_amdgcn_global_load_lds(
            (const __attribute__((address_space(1))) void*)g,
            (__attribute__((address_space(3))) void*)(smem + fb + slot * 4),
            16, 0, 0);
    }
}

__global__ __launch_bounds__(NTHR, 4) void hash_router_kernel(
    const float* __restrict__ x,   // [T, H]
    const float* __restrict__ w,   // [64, H]
    const float* __restrict__ b,   // [64]
    float* __restrict__ out,       // [2T | 2T | 64T]
    int T)
{
    __shared__ float smem[2 * BUF];                 // 40960 B exactly -> 4 blocks/CU
    // bitw overlaid into smem AFTER the main loop (reduce tree only uses
    // float slots [0, 2048); bitw lives at [2048, 2080)).
    unsigned int* bitw = (unsigned int*)(smem + 2048);

    const int tid = threadIdx.x;
    const int og  = tid & 7;          // outputs og*8 .. og*8+7
    const int tg  = (tid >> 3) & 1;   // tokens  tg*8 .. tg*8+7
    const int kg  = tid >> 4;         // K-sixteenth (0..15): k4 = kg per chunk
    const int tok0 = blockIdx.x * TOK;

    float acc[8][8];
#pragma unroll
    for (int i = 0; i < 8; ++i)
#pragma unroll
        for (int j = 0; j < 8; ++j) acc[i][j] = 0.f;

    stage_chunk(x, w, smem, 0, tok0, 0, tid);

    for (int ch = 0; ch < NCHUNK; ++ch) {
        __builtin_amdgcn_s_waitcnt(0x0f70);   // vmcnt(0): chunk ch landed
        __syncthreads();
        if (ch + 1 < NCHUNK)                  // prefetch flies during compute
            stage_chunk(x, w, smem, ((ch + 1) & 1) * BUF, tok0, (ch + 1) * KC, tid);

        const int fb = (ch & 1) * BUF;
        const int k4 = kg;                    // one k4 per thread per chunk
        float4 xv[8];
#pragma unroll
        for (int i = 0; i < 8; ++i) {
            const int row = tg * 8 + i;
            xv[i] = *(const float4*)(smem + fb + row * KC + ((k4 ^ sw_of(row)) << 2));
        }
#pragma unroll
        for (int j = 0; j < 8; ++j) {
            const int row = og * 8 + j;
            const float4 wv = *(const float4*)(smem + fb + XF + row * KC + ((k4 ^ sw_of(row)) << 2));
#pragma unroll
            for (int i = 0; i < 8; ++i) {
                acc[i][j] += xv[i].x * wv.x;
                acc[i][j] += xv[i].y * wv.y;
                acc[i][j] += xv[i].z * wv.z;
                acc[i][j] += xv[i].w * wv.w;
            }
        }
    }

    // ---- K-split reduce. 16 -> 4 in-register: tid bits 4,5 are kg bits 0,1,
    // so two shfl_xor butterflies fold kg{+1} and kg{+2}; every lane ends with
    // its wave's 4-kg sum. Then the swizzled LDS tree folds the 4 waves.
    __syncthreads();                      // buf readers done; smem reusable
#pragma unroll
    for (int i = 0; i < 8; ++i)
#pragma unroll
        for (int j = 0; j < 8; ++j) {
            acc[i][j] += __shfl_xor(acc[i][j], 16, 64);
            acc[i][j] += __shfl_xor(acc[i][j], 32, 64);
        }

    const int v    = tid >> 6;            // wave index = K-quarter (0..3)
    const int lane = tid & 63;
    const bool red = lane < 16;           // one lane per (tg,og) slot
    const int s    = tid & 15;            // (tg,og) slot id
    const int sw   = s & 7;
#define ACC_PACK(f4) make_float4(acc[(f4) >> 1][((f4) & 1) * 4],     \
                                 acc[(f4) >> 1][((f4) & 1) * 4 + 1], \
                                 acc[(f4) >> 1][((f4) & 1) * 4 + 2], \
                                 acc[(f4) >> 1][((f4) & 1) * 4 + 3])
#define ACC_ADD(f4, val) { acc[(f4) >> 1][((f4) & 1) * 4]     += (val).x; \
                           acc[(f4) >> 1][((f4) & 1) * 4 + 1] += (val).y; \
                           acc[(f4) >> 1][((f4) & 1) * 4 + 2] += (val).z; \
                           acc[(f4) >> 1][((f4) & 1) * 4 + 3] += (val).w; }
    if (v >= 2 && red) {
        float* base = smem + ((v - 2) * 16 + s) * 64;
#pragma unroll
        for (int f4 = 0; f4 < 16; ++f4) *(float4*)(base + ((f4 ^ sw) << 2)) = ACC_PACK(f4);
    }
    if (v == 0 && lane >= 16 && lane < 48) bitw[lane - 16] = 0u;  // 32 uints
    __syncthreads();
    if (v < 2 && red) {
        const float* base = smem + (v * 16 + s) * 64;
#pragma unroll
        for (int f4 = 0; f4 < 16; ++f4) { float4 t = *(const float4*)(base + ((f4 ^ sw) << 2)); ACC_ADD(f4, t); }
    }
    __syncthreads();
    if (v == 1 && red) {
        float* base = smem + s * 64;
#pragma unroll
        for (int f4 = 0; f4 < 16; ++f4) *(float4*)(base + ((f4 ^ sw) << 2)) = ACC_PACK(f4);
    }
    __syncthreads();

    if (v == 0 && red) {                  // tids 0..15, one per (tg,og) tile
        const float* base = smem + s * 64;
#pragma unroll
        for (int f4 = 0; f4 < 16; ++f4) { float4 t = *(const float4*)(base + ((f4 ^ sw) << 2)); ACC_ADD(f4, t); }

        float bias[8];
#pragma unroll
        for (int j = 0; j < 8; ++j) bias[j] = b[og * 8 + j];

        // Sign extraction; |h| within fp32-noise of 0 -> exact fp64 recheck
        // (~100 dots GPU-wide, negligible).
        const float TH = 5e-5f;
#pragma unroll
        for (int i = 0; i < 8; ++i) {
            unsigned int byte = 0u;
#pragma unroll
            for (int j = 0; j < 8; ++j) {
                const float hv = acc[i][j] + bias[j];
                bool pos;
                if (__builtin_expect(fabsf(hv) < TH, 0)) {
                    const float* xr = x + (size_t)(tok0 + tg * 8 + i) * H_DIM;
                    const float* wr = w + (size_t)(og * 8 + j) * H_DIM;
                    double sd = (double)bias[j];
                    for (int k = 0; k < H_DIM; ++k)
                        sd += (double)xr[k] * (double)wr[k];
                    pos = (sd > 0.0);
                } else {
                    pos = (hv > 0.0f);
                }
                byte |= (pos ? 1u : 0u) << j;
            }
            // outs og*8.. all in 32-bit group og>>2; position within group
            // is irrelevant (only popcount matters)
            if (byte) atomicOr(&bitw[(tg * 8 + i) * 2 + (og >> 2)], byte << ((og & 3) * 8));
        }
    }
    __syncthreads();

    if (tid < TOK) {
        const int t  = tok0 + tid;
        const int c0 = __popc(bitw[tid * 2 + 0]);
        const int c1 = __popc(bitw[tid * 2 + 1]);
        const int i1 = c1 + ((c1 == c0) ? 1 : 0);
        float2 wq; wq.x = 0.5f; wq.y = 0.5f;
        *(float2*)(out + 2 * (size_t)t) = wq;
        float2 iq; iq.x = (float)c0; iq.y = (float)i1;
        *(float2*)(out + 2 * (size_t)T + 2 * (size_t)t) = iq;
    }

    // router_logits = 0 (d_out re-poisoned 0xAA before every timed launch)
    float4 z; z.x = 0.f; z.y = 0.f; z.z = 0.f; z.w = 0.f;
    float* lbase = out + 4 * (size_t)T + (size_t)tok0 * NJ;
#pragma unroll
    for (int i = tid; i < TOK * NJ / 4; i += NTHR)
        *(float4*)(lbase + i * 4) = z;
}

extern "C" void kernel_launch(void* const* d_in, const int* in_sizes, int n_in,
                              void* d_out, int out_size, void* d_ws, size_t ws_size,
                              hipStream_t stream) {
    const float* x = (const float*)d_in[0];
    const float* w = (const float*)d_in[1];
    const float* b = (const float*)d_in[2];
    float* out = (float*)d_out;
    const int T = in_sizes[0] / H_DIM;      // 16384
    const int grid = T / TOK;               // 1024
    hash_router_kernel<<<dim3(grid), dim3(NTHR), 0, stream>>>(x, w, b, out, T);
}

// Round 5
// 320.446 us; speedup vs baseline: 1.0790x; 1.0738x over previous
//
#include <hip/hip_runtime.h>

// HashRouter: h = x @ W^T + b (T x 64), cand = popcount of sign bits per
// 32-output group; i0 = c0, i1 = c1 + (c1==c0).
// Outputs (float32, concat): weights[T][2]=0.5, indices[T][2], logits[T][64]=0.
//
// R8 == R6 resubmitted (two container-level infra failures on identical
// source; body audited clean: bounded addresses, unconditional barriers,
// fixed-trip loops -- nothing can kill a container). R6 rationale: R4/R5
// showed __launch_bounds__(.,4) clamps the allocator to 64 VGPRs
// (cap ~= 256/min_waves) -> 29 regs of acc/xv spilled -> 30 MB scratch
// WRITE_SIZE -> regression. (.,2) caps at 128, the natural ~124 footprint
// fits (R3 evidence), and <=128 VGPR is exactly what the HW needs to
// co-schedule 4 waves/SIMD anyway -- residency comes from actual VGPR/LDS,
// not the declared minimum. Kept from R5: TOK=16 -> grid=1024 -> 4 blocks/CU,
// LDS exactly 40960 B (2 x (16+64)*64 floats, bitw overlaid post-loop),
// 16-way K-split, 16->4 in-register shfl_xor fold + swizzled 4->2->1 LDS tree.
// Known second-order cost: wv reads are 4-way bank-conflicted (structural to
// TOK=16: 32 distinct lines/wave over 8 bank-groups), ~7 us total.

constexpr int H_DIM  = 2048;
constexpr int NJ     = 64;             // hash outputs
constexpr int TOK    = 16;             // tokens per block
constexpr int KC     = 64;             // k-chunk (floats) staged per row
constexpr int NCHUNK = H_DIM / KC;     // 32
constexpr int XF     = TOK * KC;       // 1024 floats per x buffer
constexpr int WF     = NJ * KC;        // 4096 floats per w buffer
constexpr int BUF    = XF + WF;        // 5120 floats (20 KB) per buffer
constexpr int XSLOTS = XF / 4;         // 256 float4 slots (x region)
constexpr int NTHR   = 256;            // threads per block (4 waves)
constexpr int SLOTS  = BUF / 4;        // 1280 float4 slots per buffer

// Row swizzle for k4-column permutation. wv reads: 32 distinct f4s/wave spread
// 4/bank-quad (4-way, ~1.58x on a lightly-loaded pipe); xv reads free.
__device__ __forceinline__ int sw_of(int row) {
    return (3 * (row >> 3) + ((row >> 2) & 1)) & 7;
}

// Async 16B global->LDS DMA. LDS dest is wave-uniform base + lane*16 (m104),
// so LDS layout is lane-linear and the swizzle is applied to the GLOBAL column
// instead: LDS[row][c4p] holds global column (c4p ^ sw_of(row)).
__device__ __forceinline__ void stage_chunk(const float* __restrict__ x,
                                            const float* __restrict__ w,
                                            float* smem, int fb,
                                            int tok0, int k0, int tid) {
#pragma unroll
    for (int it = 0; it < SLOTS / NTHR; ++it) {        // 5 iters
        const int slot = it * NTHR + tid;              // 1280 slots: 256 x, 1024 w
        const float* g;
        if (slot < XSLOTS) {
            const int row = slot >> 4, c4p = slot & 15;
            g = x + (size_t)(tok0 + row) * H_DIM + k0 + ((c4p ^ sw_of(row)) << 2);
        } else {
            const int s2 = slot - XSLOTS;
            const int row = s2 >> 4, c4p = s2 & 15;
            g = w + (size_t)row * H_DIM + k0 + ((c4p ^ sw_of(row)) << 2);
        }
        __builtin_amdgcn_global_load_lds(
            (const __attribute__((address_space(1))) void*)g,
            (__attribute__((address_space(3))) void*)(smem + fb + slot * 4),
            16, 0, 0);
    }
}

__global__ __launch_bounds__(NTHR, 2) void hash_router_kernel(
    const float* __restrict__ x,   // [T, H]
    const float* __restrict__ w,   // [64, H]
    const float* __restrict__ b,   // [64]
    float* __restrict__ out,       // [2T | 2T | 64T]
    int T)
{
    __shared__ float smem[2 * BUF];                 // 40960 B exactly -> 4 blocks/CU
    // bitw overlaid into smem AFTER the main loop (reduce tree only uses
    // float slots [0, 2048); bitw lives at [2048, 2080)).
    unsigned int* bitw = (unsigned int*)(smem + 2048);

    const int tid = threadIdx.x;
    const int og  = tid & 7;          // outputs og*8 .. og*8+7
    const int tg  = (tid >> 3) & 1;   // tokens  tg*8 .. tg*8+7
    const int kg  = tid >> 4;         // K-sixteenth (0..15): k4 = kg per chunk
    const int tok0 = blockIdx.x * TOK;

    float acc[8][8];
#pragma unroll
    for (int i = 0; i < 8; ++i)
#pragma unroll
        for (int j = 0; j < 8; ++j) acc[i][j] = 0.f;

    stage_chunk(x, w, smem, 0, tok0, 0, tid);

    for (int ch = 0; ch < NCHUNK; ++ch) {
        __builtin_amdgcn_s_waitcnt(0x0f70);   // vmcnt(0): chunk ch landed
        __syncthreads();
        if (ch + 1 < NCHUNK)                  // prefetch flies during compute
            stage_chunk(x, w, smem, ((ch + 1) & 1) * BUF, tok0, (ch + 1) * KC, tid);

        const int fb = (ch & 1) * BUF;
        const int k4 = kg;                    // one k4 per thread per chunk
        float4 xv[8];
#pragma unroll
        for (int i = 0; i < 8; ++i) {
            const int row = tg * 8 + i;
            xv[i] = *(const float4*)(smem + fb + row * KC + ((k4 ^ sw_of(row)) << 2));
        }
#pragma unroll
        for (int j = 0; j < 8; ++j) {
            const int row = og * 8 + j;
            const float4 wv = *(const float4*)(smem + fb + XF + row * KC + ((k4 ^ sw_of(row)) << 2));
#pragma unroll
            for (int i = 0; i < 8; ++i) {
                acc[i][j] += xv[i].x * wv.x;
                acc[i][j] += xv[i].y * wv.y;
                acc[i][j] += xv[i].z * wv.z;
                acc[i][j] += xv[i].w * wv.w;
            }
        }
    }

    // ---- K-split reduce. 16 -> 4 in-register: tid bits 4,5 are kg bits 0,1,
    // so two shfl_xor butterflies fold kg{+1} and kg{+2}; every lane ends with
    // its wave's 4-kg sum. Then the swizzled LDS tree folds the 4 waves.
    __syncthreads();                      // buf readers done; smem reusable
#pragma unroll
    for (int i = 0; i < 8; ++i)
#pragma unroll
        for (int j = 0; j < 8; ++j) {
            acc[i][j] += __shfl_xor(acc[i][j], 16, 64);
            acc[i][j] += __shfl_xor(acc[i][j], 32, 64);
        }

    const int v    = tid >> 6;            // wave index = K-quarter (0..3)
    const int lane = tid & 63;
    const bool red = lane < 16;           // one lane per (tg,og) slot
    const int s    = tid & 15;            // (tg,og) slot id
    const int sw   = s & 7;
#define ACC_PACK(f4) make_float4(acc[(f4) >> 1][((f4) & 1) * 4],     \
                                 acc[(f4) >> 1][((f4) & 1) * 4 + 1], \
                                 acc[(f4) >> 1][((f4) & 1) * 4 + 2], \
                                 acc[(f4) >> 1][((f4) & 1) * 4 + 3])
#define ACC_ADD(f4, val) { acc[(f4) >> 1][((f4) & 1) * 4]     += (val).x; \
                           acc[(f4) >> 1][((f4) & 1) * 4 + 1] += (val).y; \
                           acc[(f4) >> 1][((f4) & 1) * 4 + 2] += (val).z; \
                           acc[(f4) >> 1][((f4) & 1) * 4 + 3] += (val).w; }
    if (v >= 2 && red) {
        float* base = smem + ((v - 2) * 16 + s) * 64;
#pragma unroll
        for (int f4 = 0; f4 < 16; ++f4) *(float4*)(base + ((f4 ^ sw) << 2)) = ACC_PACK(f4);
    }
    if (v == 0 && lane >= 16 && lane < 48) bitw[lane - 16] = 0u;  // 32 uints
    __syncthreads();
    if (v < 2 && red) {
        const float* base = smem + (v * 16 + s) * 64;
#pragma unroll
        for (int f4 = 0; f4 < 16; ++f4) { float4 t = *(const float4*)(base + ((f4 ^ sw) << 2)); ACC_ADD(f4, t); }
    }
    __syncthreads();
    if (v == 1 && red) {
        float* base = smem + s * 64;
#pragma unroll
        for (int f4 = 0; f4 < 16; ++f4) *(float4*)(base + ((f4 ^ sw) << 2)) = ACC_PACK(f4);
    }
    __syncthreads();

    if (v == 0 && red) {                  // tids 0..15, one per (tg,og) tile
        const float* base = smem + s * 64;
#pragma unroll
        for (int f4 = 0; f4 < 16; ++f4) { float4 t = *(const float4*)(base + ((f4 ^ sw) << 2)); ACC_ADD(f4, t); }

        float bias[8];
#pragma unroll
        for (int j = 0; j < 8; ++j) bias[j] = b[og * 8 + j];

        // Sign extraction; |h| within fp32-noise of 0 -> exact fp64 recheck
        // (~100 dots GPU-wide, negligible).
        const float TH = 5e-5f;
#pragma unroll
        for (int i = 0; i < 8; ++i) {
            unsigned int byte = 0u;
#pragma unroll
            for (int j = 0; j < 8; ++j) {
                const float hv = acc[i][j] + bias[j];
                bool pos;
                if (__builtin_expect(fabsf(hv) < TH, 0)) {
                    const float* xr = x + (size_t)(tok0 + tg * 8 + i) * H_DIM;
                    const float* wr = w + (size_t)(og * 8 + j) * H_DIM;
                    double sd = (double)bias[j];
                    for (int k = 0; k < H_DIM; ++k)
                        sd += (double)xr[k] * (double)wr[k];
                    pos = (sd > 0.0);
                } else {
                    pos = (hv > 0.0f);
                }
                byte |= (pos ? 1u : 0u) << j;
            }
            // outs og*8.. all in 32-bit group og>>2; position within group
            // is irrelevant (only popcount matters)
            if (byte) atomicOr(&bitw[(tg * 8 + i) * 2 + (og >> 2)], byte << ((og & 3) * 8));
        }
    }
    __syncthreads();

    if (tid < TOK) {
        const int t  = tok0 + tid;
        const int c0 = __popc(bitw[tid * 2 + 0]);
        const int c1 = __popc(bitw[tid * 2 + 1]);
        const int i1 = c1 + ((c1 == c0) ? 1 : 0);
        float2 wq; wq.x = 0.5f; wq.y = 0.5f;
        *(float2*)(out + 2 * (size_t)t) = wq;
        float2 iq; iq.x = (float)c0; iq.y = (float)i1;
        *(float2*)(out + 2 * (size_t)T + 2 * (size_t)t) = iq;
    }

    // router_logits = 0 (d_out re-poisoned 0xAA before every timed launch)
    float4 z; z.x = 0.f; z.y = 0.f; z.z = 0.f; z.w = 0.f;
    float* lbase = out + 4 * (size_t)T + (size_t)tok0 * NJ;
#pragma unroll
    for (int i = tid; i < TOK * NJ / 4; i += NTHR)
        *(float4*)(lbase + i * 4) = z;
}

extern "C" void kernel_launch(void* const* d_in, const int* in_sizes, int n_in,
                              void* d_out, int out_size, void* d_ws, size_t ws_size,
                              hipStream_t stream) {
    const float* x = (const float*)d_in[0];
    const float* w = (const float*)d_in[1];
    const float* b = (const float*)d_in[2];
    float* out = (float*)d_out;
    const int T = in_sizes[0] / H_DIM;      // 16384
    const int grid = T / TOK;               // 1024
    hash_router_kernel<<<dim3(grid), dim3(NTHR), 0, stream>>>(x, w, b, out, T);
}

// Round 6
// 297.338 us; speedup vs baseline: 1.1628x; 1.0777x over previous
//
#include <hip/hip_runtime.h>

// HashRouter: h = x @ W^T + b (T x 64), cand = popcount of sign bits per
// 32-output group; i0 = c0, i1 = c1 + (c1==c0).
// Outputs (float32, concat): weights[T][2]=0.5, indices[T][2], logits[T][64]=0.
//
// R9: pipeline the DMA, stop draining it. Evidence across R3/R5/R8: occupancy
// (11.5% vs 28.6%) does NOT predict perf; VALUBusy is pinned at 19-25% in all
// runs because every chunk ends with vmcnt(0)+__syncthreads -- a full DMA
// drain, 32x per block (the m97-structure stall). R9 = R3's proven shape
// (TOK=32, 2-way-free swizzle, 124 VGPR, 2 blocks/CU) with ONE structural
// change: 3-buffer rotation, per-chunk `s_waitcnt vmcnt(6)` + raw s_barrier
// (T3/T4). Chunk ch+1's 6 loads/wave stay in flight across the barrier;
// prefetch distance 2. Protocol safety: per-wave vmcnt(6) drains own ch-loads
// before the barrier -> after barrier ALL waves' ch-loads landed; buffer
// (ch+2)%3 was last read in compute(ch-1), finished by all waves pre-barrier.

constexpr int H_DIM  = 2048;
constexpr int NJ     = 64;             // hash outputs
constexpr int TOK    = 32;             // tokens per block
constexpr int KC     = 64;             // k-chunk (floats) staged per row
constexpr int NCHUNK = H_DIM / KC;     // 32
constexpr int XF     = TOK * KC;       // 2048 floats per x buffer
constexpr int WF     = NJ * KC;        // 4096 floats per w buffer
constexpr int BUF    = XF + WF;        // 6144 floats (24 KB) per buffer
constexpr int XSLOTS = XF / 4;         // 512 float4 slots (x region)
constexpr int NTHR   = 256;            // threads per block (4 waves)
constexpr int SLOTS  = BUF / 4;        // 1536 float4 slots per buffer

// Row swizzle for k4-column permutation. Verified by enumeration: inner-loop
// reads (rows g*8+i over og 0..7 / tg 0..3, k4 = kg*2+c) land <=2 addresses
// per bank-quad -> conflict-free (2-way is free per m136).
__device__ __forceinline__ int sw_of(int row) {
    return (3 * (row >> 3) + ((row >> 2) & 1)) & 7;
}

// Async 16B global->LDS DMA. LDS dest is wave-uniform base + lane*16 (m104),
// so LDS layout is lane-linear and the swizzle is applied to the GLOBAL column
// instead: LDS[row][c4p] holds global column (c4p ^ sw_of(row)).
__device__ __forceinline__ void stage_chunk(const float* __restrict__ x,
                                            const float* __restrict__ w,
                                            float* smem, int fb,
                                            int tok0, int k0, int tid) {
#pragma unroll
    for (int it = 0; it < SLOTS / NTHR; ++it) {        // 6 loads per thread
        const int slot = it * NTHR + tid;              // 1536 slots: 512 x, 1024 w
        const float* g;
        if (slot < XSLOTS) {
            const int row = slot >> 4, c4p = slot & 15;
            g = x + (size_t)(tok0 + row) * H_DIM + k0 + ((c4p ^ sw_of(row)) << 2);
        } else {
            const int s2 = slot - XSLOTS;
            const int row = s2 >> 4, c4p = s2 & 15;
            g = w + (size_t)row * H_DIM + k0 + ((c4p ^ sw_of(row)) << 2);
        }
        __builtin_amdgcn_global_load_lds(
            (const __attribute__((address_space(1))) void*)g,
            (__attribute__((address_space(3))) void*)(smem + fb + slot * 4),
            16, 0, 0);
    }
}

__global__ __launch_bounds__(NTHR, 2) void hash_router_kernel(
    const float* __restrict__ x,   // [T, H]
    const float* __restrict__ w,   // [64, H]
    const float* __restrict__ b,   // [64]
    float* __restrict__ out,       // [2T | 2T | 64T]
    int T)
{
    __shared__ float smem[3 * BUF];                 // 72 KB: 3-deep ring (also reduce area)
    __shared__ unsigned int bitw[TOK][2];

    const int tid = threadIdx.x;
    const int og  = tid & 7;          // outputs og*8 .. og*8+7
    const int tg  = (tid >> 3) & 3;   // tokens  tg*8 .. tg*8+7
    const int kg  = tid >> 5;         // K-eighth: k4 in {kg*2, kg*2+1} per chunk
    const int tok0 = blockIdx.x * TOK;

    if (tid < TOK * 2) ((unsigned int*)bitw)[tid] = 0u;

    float acc[8][8];
#pragma unroll
    for (int i = 0; i < 8; ++i)
#pragma unroll
        for (int j = 0; j < 8; ++j) acc[i][j] = 0.f;

    auto compute_chunk = [&](int fb) {
#pragma unroll
        for (int c = 0; c < 2; ++c) {
            const int k4 = kg * 2 + c;
            float4 xv[8];
#pragma unroll
            for (int i = 0; i < 8; ++i) {
                const int row = tg * 8 + i;
                xv[i] = *(const float4*)(smem + fb + row * KC + ((k4 ^ sw_of(row)) << 2));
            }
#pragma unroll
            for (int j = 0; j < 8; ++j) {
                const int row = og * 8 + j;
                const float4 wv = *(const float4*)(smem + fb + XF + row * KC + ((k4 ^ sw_of(row)) << 2));
#pragma unroll
                for (int i = 0; i < 8; ++i) {
                    acc[i][j] += xv[i].x * wv.x;
                    acc[i][j] += xv[i].y * wv.y;
                    acc[i][j] += xv[i].z * wv.z;
                    acc[i][j] += xv[i].w * wv.w;
                }
            }
        }
    };

    // Prologue: 2 chunks in flight (12 outstanding loads/wave).
    stage_chunk(x, w, smem, 0,   tok0, 0,  tid);
    stage_chunk(x, w, smem, BUF, tok0, KC, tid);

    int fb_c = 0, fb_n = BUF, fb_s = 2 * BUF;   // compute / in-flight / stage
    for (int ch = 0; ch < NCHUNK - 1; ++ch) {
        // Drain own chunk-ch loads (6 newest = ch+1's stay in flight), then
        // barrier: all waves' ch-loads have landed. NO full drain.
        asm volatile("s_waitcnt vmcnt(6)" ::: "memory");
        __builtin_amdgcn_s_barrier();
        asm volatile("" ::: "memory");
        if (ch + 2 < NCHUNK)                  // refill the ring 2 chunks ahead
            stage_chunk(x, w, smem, fb_s, tok0, (ch + 2) * KC, tid);
        compute_chunk(fb_c);
        const int t = fb_c; fb_c = fb_n; fb_n = fb_s; fb_s = t;
    }
    // Tail: only chunk 31's 6 loads remain.
    asm volatile("s_waitcnt vmcnt(0)" ::: "memory");
    __builtin_amdgcn_s_barrier();
    asm volatile("" ::: "memory");
    compute_chunk(fb_c);

    // ---- K-split tree reduce (8 -> 4 -> 2 -> 1), swizzled to avoid conflicts.
    __syncthreads();                      // buf readers done; smem reusable
    const int s  = tid & 31;              // (tg,og) slot id
    const int sw = s & 7;
#define ACC_PACK(f4) make_float4(acc[(f4) >> 1][((f4) & 1) * 4],     \
                                 acc[(f4) >> 1][((f4) & 1) * 4 + 1], \
                                 acc[(f4) >> 1][((f4) & 1) * 4 + 2], \
                                 acc[(f4) >> 1][((f4) & 1) * 4 + 3])
#define ACC_ADD(f4, v) { acc[(f4) >> 1][((f4) & 1) * 4]     += (v).x; \
                         acc[(f4) >> 1][((f4) & 1) * 4 + 1] += (v).y; \
                         acc[(f4) >> 1][((f4) & 1) * 4 + 2] += (v).z; \
                         acc[(f4) >> 1][((f4) & 1) * 4 + 3] += (v).w; }
    if (kg >= 4) {
        float* base = smem + ((kg - 4) * 32 + s) * 64;
#pragma unroll
        for (int f4 = 0; f4 < 16; ++f4) *(float4*)(base + ((f4 ^ sw) << 2)) = ACC_PACK(f4);
    }
    __syncthreads();
    if (kg < 4) {
        const float* base = smem + (kg * 32 + s) * 64;
#pragma unroll
        for (int f4 = 0; f4 < 16; ++f4) { float4 v = *(const float4*)(base + ((f4 ^ sw) << 2)); ACC_ADD(f4, v); }
    }
    __syncthreads();
    if (kg == 2 || kg == 3) {
        float* base = smem + ((kg - 2) * 32 + s) * 64;
#pragma unroll
        for (int f4 = 0; f4 < 16; ++f4) *(float4*)(base + ((f4 ^ sw) << 2)) = ACC_PACK(f4);
    }
    __syncthreads();
    if (kg < 2) {
        const float* base = smem + (kg * 32 + s) * 64;
#pragma unroll
        for (int f4 = 0; f4 < 16; ++f4) { float4 v = *(const float4*)(base + ((f4 ^ sw) << 2)); ACC_ADD(f4, v); }
    }
    __syncthreads();
    if (kg == 1) {
        float* base = smem + s * 64;
#pragma unroll
        for (int f4 = 0; f4 < 16; ++f4) *(float4*)(base + ((f4 ^ sw) << 2)) = ACC_PACK(f4);
    }
    __syncthreads();

    if (kg == 0) {
        const float* base = smem + s * 64;
#pragma unroll
        for (int f4 = 0; f4 < 16; ++f4) { float4 v = *(const float4*)(base + ((f4 ^ sw) << 2)); ACC_ADD(f4, v); }

        float bias[8];
#pragma unroll
        for (int j = 0; j < 8; ++j) bias[j] = b[og * 8 + j];

        // Sign extraction; |h| within fp32-noise of 0 -> exact fp64 recheck
        // (~100 dots GPU-wide, negligible).
        const float TH = 5e-5f;
#pragma unroll
        for (int i = 0; i < 8; ++i) {
            unsigned int byte = 0u;
#pragma unroll
            for (int j = 0; j < 8; ++j) {
                const float v = acc[i][j] + bias[j];
                bool pos;
                if (__builtin_expect(fabsf(v) < TH, 0)) {
                    const float* xr = x + (size_t)(tok0 + tg * 8 + i) * H_DIM;
                    const float* wr = w + (size_t)(og * 8 + j) * H_DIM;
                    double sd = (double)bias[j];
                    for (int k = 0; k < H_DIM; ++k)
                        sd += (double)xr[k] * (double)wr[k];
                    pos = (sd > 0.0);
                } else {
                    pos = (v > 0.0f);
                }
                byte |= (pos ? 1u : 0u) << j;
            }
            // outs og*8.. all in 32-bit group og>>2; position within group
            // is irrelevant (only popcount matters)
            if (byte) atomicOr(&bitw[tg * 8 + i][og >> 2], byte << ((og & 3) * 8));
        }
    }
    __syncthreads();

    if (tid < TOK) {
        const int t  = tok0 + tid;
        const int c0 = __popc(bitw[tid][0]);
        const int c1 = __popc(bitw[tid][1]);
        const int i1 = c1 + ((c1 == c0) ? 1 : 0);
        float2 wq; wq.x = 0.5f; wq.y = 0.5f;
        *(float2*)(out + 2 * (size_t)t) = wq;
        float2 iq; iq.x = (float)c0; iq.y = (float)i1;
        *(float2*)(out + 2 * (size_t)T + 2 * (size_t)t) = iq;
    }

    // router_logits = 0 (d_out re-poisoned 0xAA before every timed launch)
    float4 z; z.x = 0.f; z.y = 0.f; z.z = 0.f; z.w = 0.f;
    float* lbase = out + 4 * (size_t)T + (size_t)tok0 * NJ;
#pragma unroll
    for (int i = tid; i < TOK * NJ / 4; i += NTHR)
        *(float4*)(lbase + i * 4) = z;
}

extern "C" void kernel_launch(void* const* d_in, const int* in_sizes, int n_in,
                              void* d_out, int out_size, void* d_ws, size_t ws_size,
                              hipStream_t stream) {
    const float* x = (const float*)d_in[0];
    const float* w = (const float*)d_in[1];
    const float* b = (const float*)d_in[2];
    float* out = (float*)d_out;
    const int T = in_sizes[0] / H_DIM;      // 16384
    const int grid = T / TOK;               // 512
    hash_router_kernel<<<dim3(grid), dim3(256), 0, stream>>>(x, w, b, out, T);
}